// Round 14
// baseline (228.203 us; speedup 1.0000x reference)
//
#include <hip/hip_runtime.h>

typedef __attribute__((ext_vector_type(8))) short short8;
typedef __attribute__((ext_vector_type(4))) float f32x4;
typedef __attribute__((ext_vector_type(4))) unsigned short u16x4;
typedef __attribute__((ext_vector_type(8))) unsigned short u16x8;

__device__ __forceinline__ unsigned short f2bf(float f) {
  union { float f; unsigned u; } v; v.f = f;
  unsigned r = v.u + 0x7FFFu + ((v.u >> 16) & 1u);
  return (unsigned short)(r >> 16);
}

#define GLL16(g, l) \
  __builtin_amdgcn_global_load_lds((const __attribute__((address_space(1))) void*)(g), \
                                   (__attribute__((address_space(3))) void*)(l), 16, 0, 0)

// ---------------- fused prep: cast x + transpose 4 weight matrices, one dispatch ----------
__device__ __forceinline__ void tpose_body(const float* __restrict__ in,
                                           unsigned short* __restrict__ out,
                                           int C, int ldo, int c0, int r0,
                                           float (*tile)[33], int tx, int ty) {
#pragma unroll
  for (int i = 0; i < 4; ++i)
    tile[ty + i * 8][tx] = in[(size_t)(r0 + ty + i * 8) * C + c0 + tx];
  __syncthreads();
#pragma unroll
  for (int i = 0; i < 4; ++i)
    out[(size_t)(c0 + ty + i * 8) * ldo + r0 + tx] = f2bf(tile[tx][ty + i * 8]);
}

__global__ __launch_bounds__(256) void prep_kernel(const float* __restrict__ x,
                                                   const float* __restrict__ Wq,
                                                   const float* __restrict__ Wk,
                                                   const float* __restrict__ Wv,
                                                   const float* __restrict__ Wo,
                                                   unsigned short* __restrict__ xb,
                                                   unsigned short* __restrict__ wqkvt,
                                                   unsigned short* __restrict__ wot) {
  __shared__ float tile[32][33];
  const int bid = blockIdx.x;
  if (bid < 4096) {  // cast x: 8 fp32 -> bf16 per thread
    const int i = bid * 256 + threadIdx.x;
    const f32x4* p = (const f32x4*)x;
    f32x4 a = p[2 * i], b = p[2 * i + 1];
    u16x8 r;
    r[0] = f2bf(a[0]); r[1] = f2bf(a[1]); r[2] = f2bf(a[2]); r[3] = f2bf(a[3]);
    r[4] = f2bf(b[0]); r[5] = f2bf(b[1]); r[6] = f2bf(b[2]); r[7] = f2bf(b[3]);
    ((u16x8*)xb)[i] = r;
    return;
  }
  const int tx = threadIdx.x & 31, ty = threadIdx.x >> 5;
  int b2 = bid - 4096;
  if (b2 < 4096) {  // Wq [2048][2048] -> wqkvt rows 0..2047
    tpose_body(Wq, wqkvt, 2048, 2048, (b2 & 63) * 32, (b2 >> 6) * 32, tile, tx, ty);
    return;
  }
  b2 -= 4096;
  if (b2 < 1024) {  // Wk [2048][512] -> wqkvt rows 2048..2559
    tpose_body(Wk, wqkvt + (size_t)2048 * 2048, 512, 2048, (b2 & 15) * 32, (b2 >> 4) * 32, tile, tx, ty);
    return;
  }
  b2 -= 1024;
  if (b2 < 1024) {  // Wv [2048][512] -> wqkvt rows 2560..3071
    tpose_body(Wv, wqkvt + (size_t)2560 * 2048, 512, 2048, (b2 & 15) * 32, (b2 >> 4) * 32, tile, tx, ty);
    return;
  }
  b2 -= 1024;  // Wo [2048][2048] -> wot
  tpose_body(Wo, wot, 2048, 2048, (b2 & 63) * 32, (b2 >> 6) * 32, tile, tx, ty);
}

// ---- GEMM: C = A[M,2048] * BT[N,2048]^T, 128x128 tile, BK=32, 8 waves ----
// T4 counted-vmcnt pipeline: 4 staging buffers, loads issued 3 iters ahead,
// per iter: vmcnt(4) [oldest stage landed, 4 newer loads stay in flight across
// the barrier] -> s_barrier -> STAGE(kt+3) into the buffer the barrier just
// retired readers of -> compute. No vmcnt(0) drain in the main loop (m218/m201).
__global__ __launch_bounds__(512) void gemm_qkv_kernel(const unsigned short* __restrict__ A,
                                                       const unsigned short* __restrict__ BT,
                                                       unsigned short* __restrict__ Cq,
                                                       unsigned short* __restrict__ VT) {
  __shared__ unsigned short As[4][128 * 32];
  __shared__ unsigned short Bs[4][128 * 32];
  const int tid = threadIdx.x;
  const int wave = tid >> 6, lane = tid & 63;
  const int r16 = lane & 15, g = lane >> 4;
  const int n0 = blockIdx.x * 128, m0 = blockIdx.y * 128;
  const int wr = wave >> 2, wc = wave & 3;
  f32x4 acc[4][2] = {};
  const int so = tid * 16;  // 512 thr x 16B = 8KB = one full 128x32 bf16 buffer
  const int srow = so >> 6, ske = (so & 63) >> 1;

  auto STAGE = [&](int kt, int bufi) {
    const int k0 = kt * 32;
    GLL16(A + (size_t)(m0 + srow) * 2048 + k0 + ske, (char*)As[bufi] + wave * 1024);
    GLL16(BT + (size_t)(n0 + srow) * 2048 + k0 + ske, (char*)Bs[bufi] + wave * 1024);
  };
  auto COMPUTE = [&](int bufi) {
    short8 af[4], bfr[2];
#pragma unroll
    for (int mi = 0; mi < 4; ++mi) {
      const int row = wr * 64 + mi * 16 + r16;
      af[mi] = *(const short8*)((const char*)As[bufi] + row * 64 + g * 16);
    }
#pragma unroll
    for (int ni = 0; ni < 2; ++ni) {
      const int row = wc * 32 + ni * 16 + r16;
      bfr[ni] = *(const short8*)((const char*)Bs[bufi] + row * 64 + g * 16);
    }
#pragma unroll
    for (int mi = 0; mi < 4; ++mi)
#pragma unroll
      for (int ni = 0; ni < 2; ++ni)
        acc[mi][ni] = __builtin_amdgcn_mfma_f32_16x16x32_bf16(af[mi], bfr[ni], acc[mi][ni], 0, 0, 0);
  };

  STAGE(0, 0);
  STAGE(1, 1);
  STAGE(2, 2);
  for (int kt = 0; kt < 61; ++kt) {
    asm volatile("s_waitcnt vmcnt(4)" ::: "memory");
    __builtin_amdgcn_s_barrier();
    STAGE(kt + 3, (kt + 3) & 3);  // overwrites buf (kt-1)%4: readers retired by barrier
    COMPUTE(kt & 3);
  }
  asm volatile("s_waitcnt vmcnt(4)" ::: "memory");
  __builtin_amdgcn_s_barrier();
  COMPUTE(1);  // kt=61
  asm volatile("s_waitcnt vmcnt(2)" ::: "memory");
  __builtin_amdgcn_s_barrier();
  COMPUTE(2);  // kt=62
  asm volatile("s_waitcnt vmcnt(0)" ::: "memory");
  __builtin_amdgcn_s_barrier();
  COMPUTE(3);  // kt=63

  const float qs = 0.18033688f;  // 0.125 * log2(e): softmax runs in exp2 domain
#pragma unroll
  for (int mi = 0; mi < 4; ++mi) {
#pragma unroll
    for (int ni = 0; ni < 2; ++ni) {
      const int n = n0 + wc * 32 + ni * 16 + r16;
      const int mb = m0 + wr * 64 + mi * 16 + g * 4;
      f32x4 v = acc[mi][ni];
      if (n < 2560) {
        const float s = (n < 2048) ? qs : 1.0f;
#pragma unroll
        for (int r = 0; r < 4; ++r) Cq[(size_t)(mb + r) * 3072 + n] = f2bf(v[r] * s);
      } else {
        const int d = n - 2560;            // kvh*64 + dd
        const int bb = mb >> 11, s0 = mb & 2047;
        // token permutation: s = 32K+16h+4g2+r stored at 32K+8g2+4h+r, so the attn
        // kernel's B-frag (slots {4g..4g+3, 16+4g..16+4g+3}) is one contiguous b128.
        const int s0p = (s0 & ~31) | (((s0 >> 2) & 3) << 3) | (((s0 >> 4) & 1) << 2);
        u16x4 pk;
#pragma unroll
        for (int r = 0; r < 4; ++r) pk[r] = f2bf(v[r]);
        *(u16x4*)(VT + (size_t)(bb * 512 + d) * 2048 + s0p) = pk;
      }
    }
  }
}

// ---------------- out-proj GEMM: fp32 output, counted-vmcnt pipeline, 8 waves ----------
__global__ __launch_bounds__(512) void gemm_out_kernel(const unsigned short* __restrict__ A,
                                                       const unsigned short* __restrict__ BT,
                                                       float* __restrict__ Co) {
  __shared__ unsigned short As[4][128 * 32];
  __shared__ unsigned short Bs[4][128 * 32];
  const int tid = threadIdx.x;
  const int wave = tid >> 6, lane = tid & 63;
  const int r16 = lane & 15, g = lane >> 4;
  const int n0 = blockIdx.x * 128, m0 = blockIdx.y * 128;
  const int wr = wave >> 2, wc = wave & 3;
  f32x4 acc[4][2] = {};
  const int so = tid * 16;
  const int srow = so >> 6, ske = (so & 63) >> 1;

  auto STAGE = [&](int kt, int bufi) {
    const int k0 = kt * 32;
    GLL16(A + (size_t)(m0 + srow) * 2048 + k0 + ske, (char*)As[bufi] + wave * 1024);
    GLL16(BT + (size_t)(n0 + srow) * 2048 + k0 + ske, (char*)Bs[bufi] + wave * 1024);
  };
  auto COMPUTE = [&](int bufi) {
    short8 af[4], bfr[2];
#pragma unroll
    for (int mi = 0; mi < 4; ++mi) {
      const int row = wr * 64 + mi * 16 + r16;
      af[mi] = *(const short8*)((const char*)As[bufi] + row * 64 + g * 16);
    }
#pragma unroll
    for (int ni = 0; ni < 2; ++ni) {
      const int row = wc * 32 + ni * 16 + r16;
      bfr[ni] = *(const short8*)((const char*)Bs[bufi] + row * 64 + g * 16);
    }
#pragma unroll
    for (int mi = 0; mi < 4; ++mi)
#pragma unroll
      for (int ni = 0; ni < 2; ++ni)
        acc[mi][ni] = __builtin_amdgcn_mfma_f32_16x16x32_bf16(af[mi], bfr[ni], acc[mi][ni], 0, 0, 0);
  };

  STAGE(0, 0);
  STAGE(1, 1);
  STAGE(2, 2);
  for (int kt = 0; kt < 61; ++kt) {
    asm volatile("s_waitcnt vmcnt(4)" ::: "memory");
    __builtin_amdgcn_s_barrier();
    STAGE(kt + 3, (kt + 3) & 3);
    COMPUTE(kt & 3);
  }
  asm volatile("s_waitcnt vmcnt(4)" ::: "memory");
  __builtin_amdgcn_s_barrier();
  COMPUTE(1);
  asm volatile("s_waitcnt vmcnt(2)" ::: "memory");
  __builtin_amdgcn_s_barrier();
  COMPUTE(2);
  asm volatile("s_waitcnt vmcnt(0)" ::: "memory");
  __builtin_amdgcn_s_barrier();
  COMPUTE(3);

#pragma unroll
  for (int mi = 0; mi < 4; ++mi)
#pragma unroll
    for (int ni = 0; ni < 2; ++ni) {
      const int n = n0 + wc * 32 + ni * 16 + r16;
      const int mb = m0 + wr * 64 + mi * 16 + g * 4;
      f32x4 v = acc[mi][ni];
#pragma unroll
      for (int r = 0; r < 4; ++r) Co[(size_t)(mb + r) * 2048 + n] = v[r];
    }
}

// ---------------- flash attention: 8 waves x 16 q-rows, pair-granularity dbuf ----------
// (verbatim R12: verified, 77.8 us)
__global__ __launch_bounds__(512) void attn_kernel(const unsigned short* __restrict__ QKV,
                                                   const unsigned short* __restrict__ VT,
                                                   unsigned short* __restrict__ O) {
  __shared__ unsigned short Ks[4][64 * 64];
  __shared__ unsigned short Vs[4][64 * 64];
  const int tid = threadIdx.x;
  const int wave = tid >> 6, lane = tid & 63;
  const int r16 = lane & 15, g = lane >> 4;
  const int qt = blockIdx.x, bh = blockIdx.y;
  const int b = bh >> 5, h = bh & 31, kvh = h >> 2;
  const int qtok0 = b * 2048 + qt * 128 + wave * 16;
  short8 qf[2];
#pragma unroll
  for (int kh = 0; kh < 2; ++kh)
    qf[kh] = *(const short8*)(QKV + (size_t)(qtok0 + r16) * 3072 + h * 64 + kh * 32 + g * 8);
  union { unsigned u[4]; short8 s; } ones;
  ones.u[0] = ones.u[1] = ones.u[2] = ones.u[3] = 0x3F803F80u;  // bf16 1.0 x8
  f32x4 oa[4] = {};
  f32x4 lacc = {};
  const int swz = (r16 & 7) << 4;
  const int b0 = r16 * 128 + ((g * 16) ^ swz);
  const int b1 = r16 * 128 + ((64 + g * 16) ^ swz);
  const unsigned short* Kb = QKV + (size_t)b * 2048 * 3072 + 2048 + kvh * 64;
  const unsigned short* Vb = VT + (size_t)(b * 512 + kvh * 64) * 2048;
  const int so = wave * 1024 + lane * 16;  // 8 waves x 1KB = 8KB tile

  auto STAGE = [&](int t, int bufi) {
    const int kv0 = t * 64;
    const int row = so >> 7;
    const int c = ((((so >> 4) & 7) ^ (row & 7))) * 8;  // pre-swizzled global source
    GLL16(Kb + (size_t)(kv0 + row) * 3072 + c, (char*)Ks[bufi] + wave * 1024);
    GLL16(Vb + (size_t)row * 2048 + kv0 + c, (char*)Vs[bufi] + wave * 1024);
  };
  auto COMPUTE = [&](int buf) {
    f32x4 sc[4];
    __builtin_amdgcn_s_setprio(1);
#pragma unroll
    for (int jt = 0; jt < 4; ++jt) {
      short8 kf0 = *(const short8*)((const char*)Ks[buf] + jt * 2048 + b0);
      short8 kf1 = *(const short8*)((const char*)Ks[buf] + jt * 2048 + b1);
      f32x4 z = {-8.f, -8.f, -8.f, -8.f};
      z = __builtin_amdgcn_mfma_f32_16x16x32_bf16(kf0, qf[0], z, 0, 0, 0);
      z = __builtin_amdgcn_mfma_f32_16x16x32_bf16(kf1, qf[1], z, 0, 0, 0);
      sc[jt] = z;
    }
    __builtin_amdgcn_s_setprio(0);
    short8 pa[2];
    {
      unsigned pk[4][2];
#pragma unroll
      for (int jt = 0; jt < 4; ++jt) {
        float p0 = __builtin_amdgcn_exp2f(sc[jt][0]);
        float p1 = __builtin_amdgcn_exp2f(sc[jt][1]);
        float p2 = __builtin_amdgcn_exp2f(sc[jt][2]);
        float p3 = __builtin_amdgcn_exp2f(sc[jt][3]);
        asm("v_cvt_pk_bf16_f32 %0, %1, %2" : "=v"(pk[jt][0]) : "v"(p0), "v"(p1));
        asm("v_cvt_pk_bf16_f32 %0, %1, %2" : "=v"(pk[jt][1]) : "v"(p2), "v"(p3));
      }
#pragma unroll
      for (int kh = 0; kh < 2; ++kh) {
        union { unsigned u[4]; short8 s; } pu;
        pu.u[0] = pk[2 * kh][0]; pu.u[1] = pk[2 * kh][1];
        pu.u[2] = pk[2 * kh + 1][0]; pu.u[3] = pk[2 * kh + 1][1];
        pa[kh] = pu.s;
      }
    }
    __builtin_amdgcn_s_setprio(1);
    lacc = __builtin_amdgcn_mfma_f32_16x16x32_bf16(pa[0], ones.s, lacc, 0, 0, 0);
    lacc = __builtin_amdgcn_mfma_f32_16x16x32_bf16(pa[1], ones.s, lacc, 0, 0, 0);
#pragma unroll
    for (int dt = 0; dt < 4; ++dt) {
      short8 vf0 = *(const short8*)((const char*)Vs[buf] + dt * 2048 + b0);
      short8 vf1 = *(const short8*)((const char*)Vs[buf] + dt * 2048 + b1);
      oa[dt] = __builtin_amdgcn_mfma_f32_16x16x32_bf16(pa[0], vf0, oa[dt], 0, 0, 0);
      oa[dt] = __builtin_amdgcn_mfma_f32_16x16x32_bf16(pa[1], vf1, oa[dt], 0, 0, 0);
    }
    __builtin_amdgcn_s_setprio(0);
  };

  STAGE(0, 0);
  STAGE(1, 1);
  __syncthreads();
  for (int j = 0; j < 16; ++j) {
    const int cur = (j & 1) << 1;           // 0 or 2
    if (j < 15) {
      STAGE(2 * j + 2, cur ^ 2);            // idle pair
      STAGE(2 * j + 3, (cur ^ 2) + 1);
    }
    COMPUTE(cur);                           // tile 2j
    COMPUTE(cur + 1);                       // tile 2j+1
    __syncthreads();                        // drains pair staging + ends pair reads
  }
  // ---- normalize: lacc already in O-store layout (row = 4g+r, any col) ----
#pragma unroll
  for (int dt = 0; dt < 4; ++dt)
#pragma unroll
    for (int r = 0; r < 4; ++r)
      O[(size_t)(qtok0 + g * 4 + r) * 2048 + h * 64 + dt * 16 + r16] =
          f2bf(oa[dt][r] / lacc[r]);
}

extern "C" void kernel_launch(void* const* d_in, const int* in_sizes, int n_in,
                              void* d_out, int out_size, void* d_ws, size_t ws_size,
                              hipStream_t stream) {
  const float* x  = (const float*)d_in[0];
  const float* Wq = (const float*)d_in[1];
  const float* Wk = (const float*)d_in[2];
  const float* Wv = (const float*)d_in[3];
  const float* Wo = (const float*)d_in[4];
  char* w = (char*)d_ws;
  // workspace layout (bytes): xb 16MB | WqkvT 12MB | WoT 8MB | QKV 24MB | VT 4MB | O 16MB = 80MB
  unsigned short* xb    = (unsigned short*)(w);
  unsigned short* wqkvt = (unsigned short*)(w + 16777216);
  unsigned short* wot   = (unsigned short*)(w + 29360128);
  unsigned short* qkv   = (unsigned short*)(w + 37748736);
  unsigned short* vt    = (unsigned short*)(w + 62914560);
  unsigned short* ob    = (unsigned short*)(w + 67108864);
  float* out = (float*)d_out;

  prep_kernel<<<14336, 256, 0, stream>>>(x, Wq, Wk, Wv, Wo, xb, wqkvt, wot);
  gemm_qkv_kernel<<<dim3(24, 32), 512, 0, stream>>>(xb, wqkvt, qkv, vt);
  attn_kernel<<<dim3(16, 64), 512, 0, stream>>>(qkv, vt, ob);
  gemm_out_kernel<<<dim3(16, 32), 512, 0, stream>>>(ob, wot, out);
}

// Round 15
// 213.899 us; speedup vs baseline: 1.0669x; 1.0669x over previous
//
#include <hip/hip_runtime.h>

typedef __attribute__((ext_vector_type(8))) short short8;
typedef __attribute__((ext_vector_type(4))) float f32x4;
typedef __attribute__((ext_vector_type(4))) unsigned short u16x4;
typedef __attribute__((ext_vector_type(8))) unsigned short u16x8;

__device__ __forceinline__ unsigned short f2bf(float f) {
  union { float f; unsigned u; } v; v.f = f;
  unsigned r = v.u + 0x7FFFu + ((v.u >> 16) & 1u);
  return (unsigned short)(r >> 16);
}

#define GLL16(g, l) \
  __builtin_amdgcn_global_load_lds((const __attribute__((address_space(1))) void*)(g), \
                                   (__attribute__((address_space(3))) void*)(l), 16, 0, 0)

// ---------------- fused prep: cast x + transpose 4 weight matrices, one dispatch ----------
__device__ __forceinline__ void tpose_body(const float* __restrict__ in,
                                           unsigned short* __restrict__ out,
                                           int C, int ldo, int c0, int r0,
                                           float (*tile)[33], int tx, int ty) {
#pragma unroll
  for (int i = 0; i < 4; ++i)
    tile[ty + i * 8][tx] = in[(size_t)(r0 + ty + i * 8) * C + c0 + tx];
  __syncthreads();
#pragma unroll
  for (int i = 0; i < 4; ++i)
    out[(size_t)(c0 + ty + i * 8) * ldo + r0 + tx] = f2bf(tile[tx][ty + i * 8]);
}

__global__ __launch_bounds__(256) void prep_kernel(const float* __restrict__ x,
                                                   const float* __restrict__ Wq,
                                                   const float* __restrict__ Wk,
                                                   const float* __restrict__ Wv,
                                                   const float* __restrict__ Wo,
                                                   unsigned short* __restrict__ xb,
                                                   unsigned short* __restrict__ wqkvt,
                                                   unsigned short* __restrict__ wot) {
  __shared__ float tile[32][33];
  const int bid = blockIdx.x;
  if (bid < 4096) {  // cast x: 8 fp32 -> bf16 per thread
    const int i = bid * 256 + threadIdx.x;
    const f32x4* p = (const f32x4*)x;
    f32x4 a = p[2 * i], b = p[2 * i + 1];
    u16x8 r;
    r[0] = f2bf(a[0]); r[1] = f2bf(a[1]); r[2] = f2bf(a[2]); r[3] = f2bf(a[3]);
    r[4] = f2bf(b[0]); r[5] = f2bf(b[1]); r[6] = f2bf(b[2]); r[7] = f2bf(b[3]);
    ((u16x8*)xb)[i] = r;
    return;
  }
  const int tx = threadIdx.x & 31, ty = threadIdx.x >> 5;
  int b2 = bid - 4096;
  if (b2 < 4096) {  // Wq [2048][2048] -> wqkvt rows 0..2047
    tpose_body(Wq, wqkvt, 2048, 2048, (b2 & 63) * 32, (b2 >> 6) * 32, tile, tx, ty);
    return;
  }
  b2 -= 4096;
  if (b2 < 1024) {  // Wk [2048][512] -> wqkvt rows 2048..2559
    tpose_body(Wk, wqkvt + (size_t)2048 * 2048, 512, 2048, (b2 & 15) * 32, (b2 >> 4) * 32, tile, tx, ty);
    return;
  }
  b2 -= 1024;
  if (b2 < 1024) {  // Wv [2048][512] -> wqkvt rows 2560..3071
    tpose_body(Wv, wqkvt + (size_t)2560 * 2048, 512, 2048, (b2 & 15) * 32, (b2 >> 4) * 32, tile, tx, ty);
    return;
  }
  b2 -= 1024;  // Wo [2048][2048] -> wot
  tpose_body(Wo, wot, 2048, 2048, (b2 & 63) * 32, (b2 >> 6) * 32, tile, tx, ty);
}

// ---- GEMM: C = A[M,2048] * BT[N,2048]^T, 128x128 tile, BK=32, 2-phase dbuf, 8 waves ----
// R12-verified structure; added T1 XCD-chunked swizzle (1-D grid, 768 blocks):
// swz=(bid&7)*96+(bid>>3) is bijective (768%8==0); chunk = 4 m-rows x all n ->
// each A-panel's 24 readers co-resident on one XCD's L2.
__global__ __launch_bounds__(512) void gemm_qkv_kernel(const unsigned short* __restrict__ A,
                                                       const unsigned short* __restrict__ BT,
                                                       unsigned short* __restrict__ Cq,
                                                       unsigned short* __restrict__ VT) {
  __shared__ unsigned short As[2][128 * 32];
  __shared__ unsigned short Bs[2][128 * 32];
  const int tid = threadIdx.x;
  const int wave = tid >> 6, lane = tid & 63;
  const int r16 = lane & 15, g = lane >> 4;
  const int swzb = ((blockIdx.x & 7) * 96) + (blockIdx.x >> 3);
  const int n0 = (swzb % 24) * 128, m0 = (swzb / 24) * 128;
  const int wr = wave >> 2, wc = wave & 3;
  f32x4 acc[4][2] = {};
  const int so = tid * 16;  // 512 thr x 16B = 8KB = one full 128x32 bf16 buffer
  const int srow = so >> 6, ske = (so & 63) >> 1;

  auto STAGE = [&](int kt, int bufi) {
    const int k0 = kt * 32;
    GLL16(A + (size_t)(m0 + srow) * 2048 + k0 + ske, (char*)As[bufi] + wave * 1024);
    GLL16(BT + (size_t)(n0 + srow) * 2048 + k0 + ske, (char*)Bs[bufi] + wave * 1024);
  };
  STAGE(0, 0);
  __syncthreads();
  for (int kt = 0; kt < 64; ++kt) {
    const int cur = kt & 1;
    if (kt < 63) STAGE(kt + 1, cur ^ 1);
    short8 af[4], bfr[2];
#pragma unroll
    for (int mi = 0; mi < 4; ++mi) {
      const int row = wr * 64 + mi * 16 + r16;
      af[mi] = *(const short8*)((const char*)As[cur] + row * 64 + g * 16);
    }
#pragma unroll
    for (int ni = 0; ni < 2; ++ni) {
      const int row = wc * 32 + ni * 16 + r16;
      bfr[ni] = *(const short8*)((const char*)Bs[cur] + row * 64 + g * 16);
    }
#pragma unroll
    for (int mi = 0; mi < 4; ++mi)
#pragma unroll
      for (int ni = 0; ni < 2; ++ni)
        acc[mi][ni] = __builtin_amdgcn_mfma_f32_16x16x32_bf16(af[mi], bfr[ni], acc[mi][ni], 0, 0, 0);
    __syncthreads();
  }
  const float qs = 0.18033688f;  // 0.125 * log2(e): softmax runs in exp2 domain
#pragma unroll
  for (int mi = 0; mi < 4; ++mi) {
#pragma unroll
    for (int ni = 0; ni < 2; ++ni) {
      const int n = n0 + wc * 32 + ni * 16 + r16;
      const int mb = m0 + wr * 64 + mi * 16 + g * 4;
      f32x4 v = acc[mi][ni];
      if (n < 2560) {
        const float s = (n < 2048) ? qs : 1.0f;
#pragma unroll
        for (int r = 0; r < 4; ++r) Cq[(size_t)(mb + r) * 3072 + n] = f2bf(v[r] * s);
      } else {
        const int d = n - 2560;            // kvh*64 + dd
        const int bb = mb >> 11, s0 = mb & 2047;
        // token permutation: s = 32K+16h+4g2+r stored at 32K+8g2+4h+r, so the attn
        // kernel's B-frag (slots {4g..4g+3, 16+4g..16+4g+3}) is one contiguous b128.
        const int s0p = (s0 & ~31) | (((s0 >> 2) & 3) << 3) | (((s0 >> 4) & 1) << 2);
        u16x4 pk;
#pragma unroll
        for (int r = 0; r < 4; ++r) pk[r] = f2bf(v[r]);
        *(u16x4*)(VT + (size_t)(bb * 512 + d) * 2048 + s0p) = pk;
      }
    }
  }
}

// ---------------- out-proj GEMM: fp32 output, 2-phase dbuf, 8 waves, XCD swizzle ----------
__global__ __launch_bounds__(512) void gemm_out_kernel(const unsigned short* __restrict__ A,
                                                       const unsigned short* __restrict__ BT,
                                                       float* __restrict__ Co) {
  __shared__ unsigned short As[2][128 * 32];
  __shared__ unsigned short Bs[2][128 * 32];
  const int tid = threadIdx.x;
  const int wave = tid >> 6, lane = tid & 63;
  const int r16 = lane & 15, g = lane >> 4;
  const int swzb = ((blockIdx.x & 7) * 64) + (blockIdx.x >> 3);  // 512 blocks, bijective
  const int n0 = (swzb % 16) * 128, m0 = (swzb / 16) * 128;
  const int wr = wave >> 2, wc = wave & 3;
  f32x4 acc[4][2] = {};
  const int so = tid * 16;
  const int srow = so >> 6, ske = (so & 63) >> 1;

  auto STAGE = [&](int kt, int bufi) {
    const int k0 = kt * 32;
    GLL16(A + (size_t)(m0 + srow) * 2048 + k0 + ske, (char*)As[bufi] + wave * 1024);
    GLL16(BT + (size_t)(n0 + srow) * 2048 + k0 + ske, (char*)Bs[bufi] + wave * 1024);
  };
  STAGE(0, 0);
  __syncthreads();
  for (int kt = 0; kt < 64; ++kt) {
    const int cur = kt & 1;
    if (kt < 63) STAGE(kt + 1, cur ^ 1);
    short8 af[4], bfr[2];
#pragma unroll
    for (int mi = 0; mi < 4; ++mi) {
      const int row = wr * 64 + mi * 16 + r16;
      af[mi] = *(const short8*)((const char*)As[cur] + row * 64 + g * 16);
    }
#pragma unroll
    for (int ni = 0; ni < 2; ++ni) {
      const int row = wc * 32 + ni * 16 + r16;
      bfr[ni] = *(const short8*)((const char*)Bs[cur] + row * 64 + g * 16);
    }
#pragma unroll
    for (int mi = 0; mi < 4; ++mi)
#pragma unroll
      for (int ni = 0; ni < 2; ++ni)
        acc[mi][ni] = __builtin_amdgcn_mfma_f32_16x16x32_bf16(af[mi], bfr[ni], acc[mi][ni], 0, 0, 0);
    __syncthreads();
  }
#pragma unroll
  for (int mi = 0; mi < 4; ++mi)
#pragma unroll
    for (int ni = 0; ni < 2; ++ni) {
      const int n = n0 + wc * 32 + ni * 16 + r16;
      const int mb = m0 + wr * 64 + mi * 16 + g * 4;
      f32x4 v = acc[mi][ni];
#pragma unroll
      for (int r = 0; r < 4; ++r) Co[(size_t)(mb + r) * 2048 + n] = v[r];
    }
}

// ---------------- flash attention: 8 waves x 16 q-rows, pair-granularity dbuf ----------
// (verbatim R12: verified, 77.8 us)
__global__ __launch_bounds__(512) void attn_kernel(const unsigned short* __restrict__ QKV,
                                                   const unsigned short* __restrict__ VT,
                                                   unsigned short* __restrict__ O) {
  __shared__ unsigned short Ks[4][64 * 64];
  __shared__ unsigned short Vs[4][64 * 64];
  const int tid = threadIdx.x;
  const int wave = tid >> 6, lane = tid & 63;
  const int r16 = lane & 15, g = lane >> 4;
  const int qt = blockIdx.x, bh = blockIdx.y;
  const int b = bh >> 5, h = bh & 31, kvh = h >> 2;
  const int qtok0 = b * 2048 + qt * 128 + wave * 16;
  short8 qf[2];
#pragma unroll
  for (int kh = 0; kh < 2; ++kh)
    qf[kh] = *(const short8*)(QKV + (size_t)(qtok0 + r16) * 3072 + h * 64 + kh * 32 + g * 8);
  union { unsigned u[4]; short8 s; } ones;
  ones.u[0] = ones.u[1] = ones.u[2] = ones.u[3] = 0x3F803F80u;  // bf16 1.0 x8
  f32x4 oa[4] = {};
  f32x4 lacc = {};
  const int swz = (r16 & 7) << 4;
  const int b0 = r16 * 128 + ((g * 16) ^ swz);
  const int b1 = r16 * 128 + ((64 + g * 16) ^ swz);
  const unsigned short* Kb = QKV + (size_t)b * 2048 * 3072 + 2048 + kvh * 64;
  const unsigned short* Vb = VT + (size_t)(b * 512 + kvh * 64) * 2048;
  const int so = wave * 1024 + lane * 16;  // 8 waves x 1KB = 8KB tile

  auto STAGE = [&](int t, int bufi) {
    const int kv0 = t * 64;
    const int row = so >> 7;
    const int c = ((((so >> 4) & 7) ^ (row & 7))) * 8;  // pre-swizzled global source
    GLL16(Kb + (size_t)(kv0 + row) * 3072 + c, (char*)Ks[bufi] + wave * 1024);
    GLL16(Vb + (size_t)row * 2048 + kv0 + c, (char*)Vs[bufi] + wave * 1024);
  };
  auto COMPUTE = [&](int buf) {
    f32x4 sc[4];
    __builtin_amdgcn_s_setprio(1);
#pragma unroll
    for (int jt = 0; jt < 4; ++jt) {
      short8 kf0 = *(const short8*)((const char*)Ks[buf] + jt * 2048 + b0);
      short8 kf1 = *(const short8*)((const char*)Ks[buf] + jt * 2048 + b1);
      f32x4 z = {-8.f, -8.f, -8.f, -8.f};
      z = __builtin_amdgcn_mfma_f32_16x16x32_bf16(kf0, qf[0], z, 0, 0, 0);
      z = __builtin_amdgcn_mfma_f32_16x16x32_bf16(kf1, qf[1], z, 0, 0, 0);
      sc[jt] = z;
    }
    __builtin_amdgcn_s_setprio(0);
    short8 pa[2];
    {
      unsigned pk[4][2];
#pragma unroll
      for (int jt = 0; jt < 4; ++jt) {
        float p0 = __builtin_amdgcn_exp2f(sc[jt][0]);
        float p1 = __builtin_amdgcn_exp2f(sc[jt][1]);
        float p2 = __builtin_amdgcn_exp2f(sc[jt][2]);
        float p3 = __builtin_amdgcn_exp2f(sc[jt][3]);
        asm("v_cvt_pk_bf16_f32 %0, %1, %2" : "=v"(pk[jt][0]) : "v"(p0), "v"(p1));
        asm("v_cvt_pk_bf16_f32 %0, %1, %2" : "=v"(pk[jt][1]) : "v"(p2), "v"(p3));
      }
#pragma unroll
      for (int kh = 0; kh < 2; ++kh) {
        union { unsigned u[4]; short8 s; } pu;
        pu.u[0] = pk[2 * kh][0]; pu.u[1] = pk[2 * kh][1];
        pu.u[2] = pk[2 * kh + 1][0]; pu.u[3] = pk[2 * kh + 1][1];
        pa[kh] = pu.s;
      }
    }
    __builtin_amdgcn_s_setprio(1);
    lacc = __builtin_amdgcn_mfma_f32_16x16x32_bf16(pa[0], ones.s, lacc, 0, 0, 0);
    lacc = __builtin_amdgcn_mfma_f32_16x16x32_bf16(pa[1], ones.s, lacc, 0, 0, 0);
#pragma unroll
    for (int dt = 0; dt < 4; ++dt) {
      short8 vf0 = *(const short8*)((const char*)Vs[buf] + dt * 2048 + b0);
      short8 vf1 = *(const short8*)((const char*)Vs[buf] + dt * 2048 + b1);
      oa[dt] = __builtin_amdgcn_mfma_f32_16x16x32_bf16(pa[0], vf0, oa[dt], 0, 0, 0);
      oa[dt] = __builtin_amdgcn_mfma_f32_16x16x32_bf16(pa[1], vf1, oa[dt], 0, 0, 0);
    }
    __builtin_amdgcn_s_setprio(0);
  };

  STAGE(0, 0);
  STAGE(1, 1);
  __syncthreads();
  for (int j = 0; j < 16; ++j) {
    const int cur = (j & 1) << 1;           // 0 or 2
    if (j < 15) {
      STAGE(2 * j + 2, cur ^ 2);            // idle pair
      STAGE(2 * j + 3, (cur ^ 2) + 1);
    }
    COMPUTE(cur);                           // tile 2j
    COMPUTE(cur + 1);                       // tile 2j+1
    __syncthreads();                        // drains pair staging + ends pair reads
  }
  // ---- normalize: lacc already in O-store layout (row = 4g+r, any col) ----
#pragma unroll
  for (int dt = 0; dt < 4; ++dt)
#pragma unroll
    for (int r = 0; r < 4; ++r)
      O[(size_t)(qtok0 + g * 4 + r) * 2048 + h * 64 + dt * 16 + r16] =
          f2bf(oa[dt][r] / lacc[r]);
}

extern "C" void kernel_launch(void* const* d_in, const int* in_sizes, int n_in,
                              void* d_out, int out_size, void* d_ws, size_t ws_size,
                              hipStream_t stream) {
  const float* x  = (const float*)d_in[0];
  const float* Wq = (const float*)d_in[1];
  const float* Wk = (const float*)d_in[2];
  const float* Wv = (const float*)d_in[3];
  const float* Wo = (const float*)d_in[4];
  char* w = (char*)d_ws;
  // workspace layout (bytes): xb 16MB | WqkvT 12MB | WoT 8MB | QKV 24MB | VT 4MB | O 16MB = 80MB
  unsigned short* xb    = (unsigned short*)(w);
  unsigned short* wqkvt = (unsigned short*)(w + 16777216);
  unsigned short* wot   = (unsigned short*)(w + 29360128);
  unsigned short* qkv   = (unsigned short*)(w + 37748736);
  unsigned short* vt    = (unsigned short*)(w + 62914560);
  unsigned short* ob    = (unsigned short*)(w + 67108864);
  float* out = (float*)d_out;

  prep_kernel<<<14336, 256, 0, stream>>>(x, Wq, Wk, Wv, Wo, xb, wqkvt, wot);
  gemm_qkv_kernel<<<768, 512, 0, stream>>>(xb, wqkvt, qkv, vt);
  attn_kernel<<<dim3(16, 64), 512, 0, stream>>>(qkv, vt, ob);
  gemm_out_kernel<<<512, 512, 0, stream>>>(ob, wot, out);
}

// Round 16
// 210.469 us; speedup vs baseline: 1.0843x; 1.0163x over previous
//
#include <hip/hip_runtime.h>

typedef __attribute__((ext_vector_type(8))) short short8;
typedef __attribute__((ext_vector_type(4))) float f32x4;
typedef __attribute__((ext_vector_type(4))) unsigned short u16x4;
typedef __attribute__((ext_vector_type(8))) unsigned short u16x8;

__device__ __forceinline__ unsigned short f2bf(float f) {
  union { float f; unsigned u; } v; v.f = f;
  unsigned r = v.u + 0x7FFFu + ((v.u >> 16) & 1u);
  return (unsigned short)(r >> 16);
}

#define GLL16(g, l) \
  __builtin_amdgcn_global_load_lds((const __attribute__((address_space(1))) void*)(g), \
                                   (__attribute__((address_space(3))) void*)(l), 16, 0, 0)

// ---------------- fused prep: cast x + transpose 4 weight matrices, one dispatch ----------
__device__ __forceinline__ void tpose_body(const float* __restrict__ in,
                                           unsigned short* __restrict__ out,
                                           int C, int ldo, int c0, int r0,
                                           float (*tile)[33], int tx, int ty) {
#pragma unroll
  for (int i = 0; i < 4; ++i)
    tile[ty + i * 8][tx] = in[(size_t)(r0 + ty + i * 8) * C + c0 + tx];
  __syncthreads();
#pragma unroll
  for (int i = 0; i < 4; ++i)
    out[(size_t)(c0 + ty + i * 8) * ldo + r0 + tx] = f2bf(tile[tx][ty + i * 8]);
}

__global__ __launch_bounds__(256) void prep_kernel(const float* __restrict__ x,
                                                   const float* __restrict__ Wq,
                                                   const float* __restrict__ Wk,
                                                   const float* __restrict__ Wv,
                                                   const float* __restrict__ Wo,
                                                   unsigned short* __restrict__ xb,
                                                   unsigned short* __restrict__ wqkvt,
                                                   unsigned short* __restrict__ wot) {
  __shared__ float tile[32][33];
  const int bid = blockIdx.x;
  if (bid < 4096) {  // cast x: 8 fp32 -> bf16 per thread
    const int i = bid * 256 + threadIdx.x;
    const f32x4* p = (const f32x4*)x;
    f32x4 a = p[2 * i], b = p[2 * i + 1];
    u16x8 r;
    r[0] = f2bf(a[0]); r[1] = f2bf(a[1]); r[2] = f2bf(a[2]); r[3] = f2bf(a[3]);
    r[4] = f2bf(b[0]); r[5] = f2bf(b[1]); r[6] = f2bf(b[2]); r[7] = f2bf(b[3]);
    ((u16x8*)xb)[i] = r;
    return;
  }
  const int tx = threadIdx.x & 31, ty = threadIdx.x >> 5;
  int b2 = bid - 4096;
  if (b2 < 4096) {  // Wq [2048][2048] -> wqkvt rows 0..2047
    tpose_body(Wq, wqkvt, 2048, 2048, (b2 & 63) * 32, (b2 >> 6) * 32, tile, tx, ty);
    return;
  }
  b2 -= 4096;
  if (b2 < 1024) {  // Wk [2048][512] -> wqkvt rows 2048..2559
    tpose_body(Wk, wqkvt + (size_t)2048 * 2048, 512, 2048, (b2 & 15) * 32, (b2 >> 4) * 32, tile, tx, ty);
    return;
  }
  b2 -= 1024;
  if (b2 < 1024) {  // Wv [2048][512] -> wqkvt rows 2560..3071
    tpose_body(Wv, wqkvt + (size_t)2560 * 2048, 512, 2048, (b2 & 15) * 32, (b2 >> 4) * 32, tile, tx, ty);
    return;
  }
  b2 -= 1024;  // Wo [2048][2048] -> wot
  tpose_body(Wo, wot, 2048, 2048, (b2 & 63) * 32, (b2 >> 6) * 32, tile, tx, ty);
}

// ---- GEMM: C = A[M,2048] * BT[N,2048]^T, 128x128 tile, BK=32, 2-phase dbuf, 8 waves ----
// (verbatim R14: verified; T1 XCD-chunked swizzle, 768 blocks)
__global__ __launch_bounds__(512) void gemm_qkv_kernel(const unsigned short* __restrict__ A,
                                                       const unsigned short* __restrict__ BT,
                                                       unsigned short* __restrict__ Cq,
                                                       unsigned short* __restrict__ VT) {
  __shared__ unsigned short As[2][128 * 32];
  __shared__ unsigned short Bs[2][128 * 32];
  const int tid = threadIdx.x;
  const int wave = tid >> 6, lane = tid & 63;
  const int r16 = lane & 15, g = lane >> 4;
  const int swzb = ((blockIdx.x & 7) * 96) + (blockIdx.x >> 3);
  const int n0 = (swzb % 24) * 128, m0 = (swzb / 24) * 128;
  const int wr = wave >> 2, wc = wave & 3;
  f32x4 acc[4][2] = {};
  const int so = tid * 16;  // 512 thr x 16B = 8KB = one full 128x32 bf16 buffer
  const int srow = so >> 6, ske = (so & 63) >> 1;

  auto STAGE = [&](int kt, int bufi) {
    const int k0 = kt * 32;
    GLL16(A + (size_t)(m0 + srow) * 2048 + k0 + ske, (char*)As[bufi] + wave * 1024);
    GLL16(BT + (size_t)(n0 + srow) * 2048 + k0 + ske, (char*)Bs[bufi] + wave * 1024);
  };
  STAGE(0, 0);
  __syncthreads();
  for (int kt = 0; kt < 64; ++kt) {
    const int cur = kt & 1;
    if (kt < 63) STAGE(kt + 1, cur ^ 1);
    short8 af[4], bfr[2];
#pragma unroll
    for (int mi = 0; mi < 4; ++mi) {
      const int row = wr * 64 + mi * 16 + r16;
      af[mi] = *(const short8*)((const char*)As[cur] + row * 64 + g * 16);
    }
#pragma unroll
    for (int ni = 0; ni < 2; ++ni) {
      const int row = wc * 32 + ni * 16 + r16;
      bfr[ni] = *(const short8*)((const char*)Bs[cur] + row * 64 + g * 16);
    }
#pragma unroll
    for (int mi = 0; mi < 4; ++mi)
#pragma unroll
      for (int ni = 0; ni < 2; ++ni)
        acc[mi][ni] = __builtin_amdgcn_mfma_f32_16x16x32_bf16(af[mi], bfr[ni], acc[mi][ni], 0, 0, 0);
    __syncthreads();
  }
  const float qs = 0.18033688f;  // 0.125 * log2(e): softmax runs in exp2 domain
#pragma unroll
  for (int mi = 0; mi < 4; ++mi) {
#pragma unroll
    for (int ni = 0; ni < 2; ++ni) {
      const int n = n0 + wc * 32 + ni * 16 + r16;
      const int mb = m0 + wr * 64 + mi * 16 + g * 4;
      f32x4 v = acc[mi][ni];
      if (n < 2560) {
        const float s = (n < 2048) ? qs : 1.0f;
#pragma unroll
        for (int r = 0; r < 4; ++r) Cq[(size_t)(mb + r) * 3072 + n] = f2bf(v[r] * s);
      } else {
        const int d = n - 2560;            // kvh*64 + dd
        const int bb = mb >> 11, s0 = mb & 2047;
        // token permutation: s = 32K+16h+4g2+r stored at 32K+8g2+4h+r, so the attn
        // kernel's B-frag (slots {4g..4g+3, 16+4g..16+4g+3}) is one contiguous b128.
        const int s0p = (s0 & ~31) | (((s0 >> 2) & 3) << 3) | (((s0 >> 4) & 1) << 2);
        u16x4 pk;
#pragma unroll
        for (int r = 0; r < 4; ++r) pk[r] = f2bf(v[r]);
        *(u16x4*)(VT + (size_t)(bb * 512 + d) * 2048 + s0p) = pk;
      }
    }
  }
}

// ---------------- out-proj GEMM: fp32 output, 2-phase dbuf, 8 waves, XCD swizzle ----------
__global__ __launch_bounds__(512) void gemm_out_kernel(const unsigned short* __restrict__ A,
                                                       const unsigned short* __restrict__ BT,
                                                       float* __restrict__ Co) {
  __shared__ unsigned short As[2][128 * 32];
  __shared__ unsigned short Bs[2][128 * 32];
  const int tid = threadIdx.x;
  const int wave = tid >> 6, lane = tid & 63;
  const int r16 = lane & 15, g = lane >> 4;
  const int swzb = ((blockIdx.x & 7) * 64) + (blockIdx.x >> 3);  // 512 blocks, bijective
  const int n0 = (swzb % 16) * 128, m0 = (swzb / 16) * 128;
  const int wr = wave >> 2, wc = wave & 3;
  f32x4 acc[4][2] = {};
  const int so = tid * 16;
  const int srow = so >> 6, ske = (so & 63) >> 1;

  auto STAGE = [&](int kt, int bufi) {
    const int k0 = kt * 32;
    GLL16(A + (size_t)(m0 + srow) * 2048 + k0 + ske, (char*)As[bufi] + wave * 1024);
    GLL16(BT + (size_t)(n0 + srow) * 2048 + k0 + ske, (char*)Bs[bufi] + wave * 1024);
  };
  STAGE(0, 0);
  __syncthreads();
  for (int kt = 0; kt < 64; ++kt) {
    const int cur = kt & 1;
    if (kt < 63) STAGE(kt + 1, cur ^ 1);
    short8 af[4], bfr[2];
#pragma unroll
    for (int mi = 0; mi < 4; ++mi) {
      const int row = wr * 64 + mi * 16 + r16;
      af[mi] = *(const short8*)((const char*)As[cur] + row * 64 + g * 16);
    }
#pragma unroll
    for (int ni = 0; ni < 2; ++ni) {
      const int row = wc * 32 + ni * 16 + r16;
      bfr[ni] = *(const short8*)((const char*)Bs[cur] + row * 64 + g * 16);
    }
#pragma unroll
    for (int mi = 0; mi < 4; ++mi)
#pragma unroll
      for (int ni = 0; ni < 2; ++ni)
        acc[mi][ni] = __builtin_amdgcn_mfma_f32_16x16x32_bf16(af[mi], bfr[ni], acc[mi][ni], 0, 0, 0);
    __syncthreads();
  }
#pragma unroll
  for (int mi = 0; mi < 4; ++mi)
#pragma unroll
    for (int ni = 0; ni < 2; ++ni) {
      const int n = n0 + wc * 32 + ni * 16 + r16;
      const int mb = m0 + wr * 64 + mi * 16 + g * 4;
      f32x4 v = acc[mi][ni];
#pragma unroll
      for (int r = 0; r < 4; ++r) Co[(size_t)(mb + r) * 2048 + n] = v[r];
    }
}

// ---------------- flash attention: 8 waves x 16 q-rows, pair-granularity dbuf ----------
// R12-verified body; ONLY change: 1-D grid (1024) with T1 XCD-chunked swizzle —
// XCD k serves bh in [8k, 8k+8) -> 2 K/V panels (1MB) resident in its 4MB L2,
// so staging loads become L2 hits (~200cy) instead of HBM (~900cy).
__global__ __launch_bounds__(512) void attn_kernel(const unsigned short* __restrict__ QKV,
                                                   const unsigned short* __restrict__ VT,
                                                   unsigned short* __restrict__ O) {
  __shared__ unsigned short Ks[4][64 * 64];
  __shared__ unsigned short Vs[4][64 * 64];
  const int tid = threadIdx.x;
  const int wave = tid >> 6, lane = tid & 63;
  const int r16 = lane & 15, g = lane >> 4;
  const int bid = blockIdx.x;
  const int swzg = ((bid & 7) << 7) | (bid >> 3);  // bijective: 1024 % 8 == 0
  const int qt = swzg & 15, bh = swzg >> 4;
  const int b = bh >> 5, h = bh & 31, kvh = h >> 2;
  const int qtok0 = b * 2048 + qt * 128 + wave * 16;
  short8 qf[2];
#pragma unroll
  for (int kh = 0; kh < 2; ++kh)
    qf[kh] = *(const short8*)(QKV + (size_t)(qtok0 + r16) * 3072 + h * 64 + kh * 32 + g * 8);
  union { unsigned u[4]; short8 s; } ones;
  ones.u[0] = ones.u[1] = ones.u[2] = ones.u[3] = 0x3F803F80u;  // bf16 1.0 x8
  f32x4 oa[4] = {};
  f32x4 lacc = {};
  const int swz = (r16 & 7) << 4;
  const int b0 = r16 * 128 + ((g * 16) ^ swz);
  const int b1 = r16 * 128 + ((64 + g * 16) ^ swz);
  const unsigned short* Kb = QKV + (size_t)b * 2048 * 3072 + 2048 + kvh * 64;
  const unsigned short* Vb = VT + (size_t)(b * 512 + kvh * 64) * 2048;
  const int so = wave * 1024 + lane * 16;  // 8 waves x 1KB = 8KB tile

  auto STAGE = [&](int t, int bufi) {
    const int kv0 = t * 64;
    const int row = so >> 7;
    const int c = ((((so >> 4) & 7) ^ (row & 7))) * 8;  // pre-swizzled global source
    GLL16(Kb + (size_t)(kv0 + row) * 3072 + c, (char*)Ks[bufi] + wave * 1024);
    GLL16(Vb + (size_t)row * 2048 + kv0 + c, (char*)Vs[bufi] + wave * 1024);
  };
  auto COMPUTE = [&](int buf) {
    f32x4 sc[4];
    __builtin_amdgcn_s_setprio(1);
#pragma unroll
    for (int jt = 0; jt < 4; ++jt) {
      short8 kf0 = *(const short8*)((const char*)Ks[buf] + jt * 2048 + b0);
      short8 kf1 = *(const short8*)((const char*)Ks[buf] + jt * 2048 + b1);
      f32x4 z = {-8.f, -8.f, -8.f, -8.f};
      z = __builtin_amdgcn_mfma_f32_16x16x32_bf16(kf0, qf[0], z, 0, 0, 0);
      z = __builtin_amdgcn_mfma_f32_16x16x32_bf16(kf1, qf[1], z, 0, 0, 0);
      sc[jt] = z;
    }
    __builtin_amdgcn_s_setprio(0);
    short8 pa[2];
    {
      unsigned pk[4][2];
#pragma unroll
      for (int jt = 0; jt < 4; ++jt) {
        float p0 = __builtin_amdgcn_exp2f(sc[jt][0]);
        float p1 = __builtin_amdgcn_exp2f(sc[jt][1]);
        float p2 = __builtin_amdgcn_exp2f(sc[jt][2]);
        float p3 = __builtin_amdgcn_exp2f(sc[jt][3]);
        asm("v_cvt_pk_bf16_f32 %0, %1, %2" : "=v"(pk[jt][0]) : "v"(p0), "v"(p1));
        asm("v_cvt_pk_bf16_f32 %0, %1, %2" : "=v"(pk[jt][1]) : "v"(p2), "v"(p3));
      }
#pragma unroll
      for (int kh = 0; kh < 2; ++kh) {
        union { unsigned u[4]; short8 s; } pu;
        pu.u[0] = pk[2 * kh][0]; pu.u[1] = pk[2 * kh][1];
        pu.u[2] = pk[2 * kh + 1][0]; pu.u[3] = pk[2 * kh + 1][1];
        pa[kh] = pu.s;
      }
    }
    __builtin_amdgcn_s_setprio(1);
    lacc = __builtin_amdgcn_mfma_f32_16x16x32_bf16(pa[0], ones.s, lacc, 0, 0, 0);
    lacc = __builtin_amdgcn_mfma_f32_16x16x32_bf16(pa[1], ones.s, lacc, 0, 0, 0);
#pragma unroll
    for (int dt = 0; dt < 4; ++dt) {
      short8 vf0 = *(const short8*)((const char*)Vs[buf] + dt * 2048 + b0);
      short8 vf1 = *(const short8*)((const char*)Vs[buf] + dt * 2048 + b1);
      oa[dt] = __builtin_amdgcn_mfma_f32_16x16x32_bf16(pa[0], vf0, oa[dt], 0, 0, 0);
      oa[dt] = __builtin_amdgcn_mfma_f32_16x16x32_bf16(pa[1], vf1, oa[dt], 0, 0, 0);
    }
    __builtin_amdgcn_s_setprio(0);
  };

  STAGE(0, 0);
  STAGE(1, 1);
  __syncthreads();
  for (int j = 0; j < 16; ++j) {
    const int cur = (j & 1) << 1;           // 0 or 2
    if (j < 15) {
      STAGE(2 * j + 2, cur ^ 2);            // idle pair
      STAGE(2 * j + 3, (cur ^ 2) + 1);
    }
    COMPUTE(cur);                           // tile 2j
    COMPUTE(cur + 1);                       // tile 2j+1
    __syncthreads();                        // drains pair staging + ends pair reads
  }
  // ---- normalize: lacc already in O-store layout (row = 4g+r, any col) ----
#pragma unroll
  for (int dt = 0; dt < 4; ++dt)
#pragma unroll
    for (int r = 0; r < 4; ++r)
      O[(size_t)(qtok0 + g * 4 + r) * 2048 + h * 64 + dt * 16 + r16] =
          f2bf(oa[dt][r] / lacc[r]);
}

extern "C" void kernel_launch(void* const* d_in, const int* in_sizes, int n_in,
                              void* d_out, int out_size, void* d_ws, size_t ws_size,
                              hipStream_t stream) {
  const float* x  = (const float*)d_in[0];
  const float* Wq = (const float*)d_in[1];
  const float* Wk = (const float*)d_in[2];
  const float* Wv = (const float*)d_in[3];
  const float* Wo = (const float*)d_in[4];
  char* w = (char*)d_ws;
  // workspace layout (bytes): xb 16MB | WqkvT 12MB | WoT 8MB | QKV 24MB | VT 4MB | O 16MB = 80MB
  unsigned short* xb    = (unsigned short*)(w);
  unsigned short* wqkvt = (unsigned short*)(w + 16777216);
  unsigned short* wot   = (unsigned short*)(w + 29360128);
  unsigned short* qkv   = (unsigned short*)(w + 37748736);
  unsigned short* vt    = (unsigned short*)(w + 62914560);
  unsigned short* ob    = (unsigned short*)(w + 67108864);
  float* out = (float*)d_out;

  prep_kernel<<<14336, 256, 0, stream>>>(x, Wq, Wk, Wv, Wo, xb, wqkvt, wot);
  gemm_qkv_kernel<<<768, 512, 0, stream>>>(xb, wqkvt, qkv, vt);
  attn_kernel<<<1024, 512, 0, stream>>>(qkv, vt, ob);
  gemm_out_kernel<<<512, 512, 0, stream>>>(ob, wot, out);
}

// Round 19
// 209.830 us; speedup vs baseline: 1.0876x; 1.0030x over previous
//
#include <hip/hip_runtime.h>

typedef __attribute__((ext_vector_type(8))) short short8;
typedef __attribute__((ext_vector_type(4))) float f32x4;
typedef __attribute__((ext_vector_type(4))) unsigned short u16x4;
typedef __attribute__((ext_vector_type(8))) unsigned short u16x8;

__device__ __forceinline__ unsigned short f2bf(float f) {
  union { float f; unsigned u; } v; v.f = f;
  unsigned r = v.u + 0x7FFFu + ((v.u >> 16) & 1u);
  return (unsigned short)(r >> 16);
}

#define GLL16(g, l) \
  __builtin_amdgcn_global_load_lds((const __attribute__((address_space(1))) void*)(g), \
                                   (__attribute__((address_space(3))) void*)(l), 16, 0, 0)

// ---------------- fused prep: cast x + transpose 4 weight matrices, one dispatch ----------
__device__ __forceinline__ void tpose_body(const float* __restrict__ in,
                                           unsigned short* __restrict__ out,
                                           int C, int ldo, int c0, int r0,
                                           float (*tile)[33], int tx, int ty) {
#pragma unroll
  for (int i = 0; i < 4; ++i)
    tile[ty + i * 8][tx] = in[(size_t)(r0 + ty + i * 8) * C + c0 + tx];
  __syncthreads();
#pragma unroll
  for (int i = 0; i < 4; ++i)
    out[(size_t)(c0 + ty + i * 8) * ldo + r0 + tx] = f2bf(tile[tx][ty + i * 8]);
}

__global__ __launch_bounds__(256) void prep_kernel(const float* __restrict__ x,
                                                   const float* __restrict__ Wq,
                                                   const float* __restrict__ Wk,
                                                   const float* __restrict__ Wv,
                                                   const float* __restrict__ Wo,
                                                   unsigned short* __restrict__ xb,
                                                   unsigned short* __restrict__ wqkvt,
                                                   unsigned short* __restrict__ wot) {
  __shared__ float tile[32][33];
  const int bid = blockIdx.x;
  if (bid < 4096) {  // cast x: 8 fp32 -> bf16 per thread
    const int i = bid * 256 + threadIdx.x;
    const f32x4* p = (const f32x4*)x;
    f32x4 a = p[2 * i], b = p[2 * i + 1];
    u16x8 r;
    r[0] = f2bf(a[0]); r[1] = f2bf(a[1]); r[2] = f2bf(a[2]); r[3] = f2bf(a[3]);
    r[4] = f2bf(b[0]); r[5] = f2bf(b[1]); r[6] = f2bf(b[2]); r[7] = f2bf(b[3]);
    ((u16x8*)xb)[i] = r;
    return;
  }
  const int tx = threadIdx.x & 31, ty = threadIdx.x >> 5;
  int b2 = bid - 4096;
  if (b2 < 4096) {  // Wq [2048][2048] -> wqkvt rows 0..2047
    tpose_body(Wq, wqkvt, 2048, 2048, (b2 & 63) * 32, (b2 >> 6) * 32, tile, tx, ty);
    return;
  }
  b2 -= 4096;
  if (b2 < 1024) {  // Wk [2048][512] -> wqkvt rows 2048..2559
    tpose_body(Wk, wqkvt + (size_t)2048 * 2048, 512, 2048, (b2 & 15) * 32, (b2 >> 4) * 32, tile, tx, ty);
    return;
  }
  b2 -= 1024;
  if (b2 < 1024) {  // Wv [2048][512] -> wqkvt rows 2560..3071
    tpose_body(Wv, wqkvt + (size_t)2560 * 2048, 512, 2048, (b2 & 15) * 32, (b2 >> 4) * 32, tile, tx, ty);
    return;
  }
  b2 -= 1024;  // Wo [2048][2048] -> wot
  tpose_body(Wo, wot, 2048, 2048, (b2 & 63) * 32, (b2 >> 6) * 32, tile, tx, ty);
}

// ---- GEMM: C = A[M,2048] * BT[N,2048]^T, 128x128 tile, BK=32, 2-phase dbuf, 8 waves ----
// (verified R14/R15; T1 XCD-chunked swizzle, 768 blocks)
__global__ __launch_bounds__(512) void gemm_qkv_kernel(const unsigned short* __restrict__ A,
                                                       const unsigned short* __restrict__ BT,
                                                       unsigned short* __restrict__ Cq,
                                                       unsigned short* __restrict__ VT) {
  __shared__ unsigned short As[2][128 * 32];
  __shared__ unsigned short Bs[2][128 * 32];
  const int tid = threadIdx.x;
  const int wave = tid >> 6, lane = tid & 63;
  const int r16 = lane & 15, g = lane >> 4;
  const int swzb = ((blockIdx.x & 7) * 96) + (blockIdx.x >> 3);
  const int n0 = (swzb % 24) * 128, m0 = (swzb / 24) * 128;
  const int wr = wave >> 2, wc = wave & 3;
  f32x4 acc[4][2] = {};
  const int so = tid * 16;  // 512 thr x 16B = 8KB = one full 128x32 bf16 buffer
  const int srow = so >> 6, ske = (so & 63) >> 1;

  auto STAGE = [&](int kt, int bufi) {
    const int k0 = kt * 32;
    GLL16(A + (size_t)(m0 + srow) * 2048 + k0 + ske, (char*)As[bufi] + wave * 1024);
    GLL16(BT + (size_t)(n0 + srow) * 2048 + k0 + ske, (char*)Bs[bufi] + wave * 1024);
  };
  STAGE(0, 0);
  __syncthreads();
  for (int kt = 0; kt < 64; ++kt) {
    const int cur = kt & 1;
    if (kt < 63) STAGE(kt + 1, cur ^ 1);
    short8 af[4], bfr[2];
#pragma unroll
    for (int mi = 0; mi < 4; ++mi) {
      const int row = wr * 64 + mi * 16 + r16;
      af[mi] = *(const short8*)((const char*)As[cur] + row * 64 + g * 16);
    }
#pragma unroll
    for (int ni = 0; ni < 2; ++ni) {
      const int row = wc * 32 + ni * 16 + r16;
      bfr[ni] = *(const short8*)((const char*)Bs[cur] + row * 64 + g * 16);
    }
#pragma unroll
    for (int mi = 0; mi < 4; ++mi)
#pragma unroll
      for (int ni = 0; ni < 2; ++ni)
        acc[mi][ni] = __builtin_amdgcn_mfma_f32_16x16x32_bf16(af[mi], bfr[ni], acc[mi][ni], 0, 0, 0);
    __syncthreads();
  }
  const float qs = 0.18033688f;  // 0.125 * log2(e): softmax runs in exp2 domain
#pragma unroll
  for (int mi = 0; mi < 4; ++mi) {
#pragma unroll
    for (int ni = 0; ni < 2; ++ni) {
      const int n = n0 + wc * 32 + ni * 16 + r16;
      const int mb = m0 + wr * 64 + mi * 16 + g * 4;
      f32x4 v = acc[mi][ni];
      if (n < 2560) {
        const float s = (n < 2048) ? qs : 1.0f;
#pragma unroll
        for (int r = 0; r < 4; ++r) Cq[(size_t)(mb + r) * 3072 + n] = f2bf(v[r] * s);
      } else {
        const int d = n - 2560;            // kvh*64 + dd
        const int bb = mb >> 11, s0 = mb & 2047;
        // token permutation: s = 32K+16h+4g2+r stored at 32K+8g2+4h+r, so the attn
        // kernel's B-frag (slots {4g..4g+3, 16+4g..16+4g+3}) is one contiguous b128.
        const int s0p = (s0 & ~31) | (((s0 >> 2) & 3) << 3) | (((s0 >> 4) & 1) << 2);
        u16x4 pk;
#pragma unroll
        for (int r = 0; r < 4; ++r) pk[r] = f2bf(v[r]);
        *(u16x4*)(VT + (size_t)(bb * 512 + d) * 2048 + s0p) = pk;
      }
    }
  }
}

// ---------------- out-proj GEMM: fp32 output, 2-phase dbuf, 8 waves, XCD swizzle ----------
__global__ __launch_bounds__(512) void gemm_out_kernel(const unsigned short* __restrict__ A,
                                                       const unsigned short* __restrict__ BT,
                                                       float* __restrict__ Co) {
  __shared__ unsigned short As[2][128 * 32];
  __shared__ unsigned short Bs[2][128 * 32];
  const int tid = threadIdx.x;
  const int wave = tid >> 6, lane = tid & 63;
  const int r16 = lane & 15, g = lane >> 4;
  const int swzb = ((blockIdx.x & 7) * 64) + (blockIdx.x >> 3);  // 512 blocks, bijective
  const int n0 = (swzb % 16) * 128, m0 = (swzb / 16) * 128;
  const int wr = wave >> 2, wc = wave & 3;
  f32x4 acc[4][2] = {};
  const int so = tid * 16;
  const int srow = so >> 6, ske = (so & 63) >> 1;

  auto STAGE = [&](int kt, int bufi) {
    const int k0 = kt * 32;
    GLL16(A + (size_t)(m0 + srow) * 2048 + k0 + ske, (char*)As[bufi] + wave * 1024);
    GLL16(BT + (size_t)(n0 + srow) * 2048 + k0 + ske, (char*)Bs[bufi] + wave * 1024);
  };
  STAGE(0, 0);
  __syncthreads();
  for (int kt = 0; kt < 64; ++kt) {
    const int cur = kt & 1;
    if (kt < 63) STAGE(kt + 1, cur ^ 1);
    short8 af[4], bfr[2];
#pragma unroll
    for (int mi = 0; mi < 4; ++mi) {
      const int row = wr * 64 + mi * 16 + r16;
      af[mi] = *(const short8*)((const char*)As[cur] + row * 64 + g * 16);
    }
#pragma unroll
    for (int ni = 0; ni < 2; ++ni) {
      const int row = wc * 32 + ni * 16 + r16;
      bfr[ni] = *(const short8*)((const char*)Bs[cur] + row * 64 + g * 16);
    }
#pragma unroll
    for (int mi = 0; mi < 4; ++mi)
#pragma unroll
      for (int ni = 0; ni < 2; ++ni)
        acc[mi][ni] = __builtin_amdgcn_mfma_f32_16x16x32_bf16(af[mi], bfr[ni], acc[mi][ni], 0, 0, 0);
    __syncthreads();
  }
#pragma unroll
  for (int mi = 0; mi < 4; ++mi)
#pragma unroll
    for (int ni = 0; ni < 2; ++ni) {
      const int n = n0 + wc * 32 + ni * 16 + r16;
      const int mb = m0 + wr * 64 + mi * 16 + g * 4;
      f32x4 v = acc[mi][ni];
#pragma unroll
      for (int r = 0; r < 4; ++r) Co[(size_t)(mb + r) * 2048 + n] = v[r];
    }
}

// ---------------- flash attention: 8 waves x 16 q-rows, pair-granularity dbuf ----------
// (verbatim R15: verified, ~77 us; 1-D grid with XCD-chunked swizzle)
__global__ __launch_bounds__(512) void attn_kernel(const unsigned short* __restrict__ QKV,
                                                   const unsigned short* __restrict__ VT,
                                                   unsigned short* __restrict__ O) {
  __shared__ unsigned short Ks[4][64 * 64];
  __shared__ unsigned short Vs[4][64 * 64];
  const int tid = threadIdx.x;
  const int wave = tid >> 6, lane = tid & 63;
  const int r16 = lane & 15, g = lane >> 4;
  const int bid = blockIdx.x;
  const int swzg = ((bid & 7) << 7) | (bid >> 3);  // bijective: 1024 % 8 == 0
  const int qt = swzg & 15, bh = swzg >> 4;
  const int b = bh >> 5, h = bh & 31, kvh = h >> 2;
  const int qtok0 = b * 2048 + qt * 128 + wave * 16;
  short8 qf[2];
#pragma unroll
  for (int kh = 0; kh < 2; ++kh)
    qf[kh] = *(const short8*)(QKV + (size_t)(qtok0 + r16) * 3072 + h * 64 + kh * 32 + g * 8);
  union { unsigned u[4]; short8 s; } ones;
  ones.u[0] = ones.u[1] = ones.u[2] = ones.u[3] = 0x3F803F80u;  // bf16 1.0 x8
  f32x4 oa[4] = {};
  f32x4 lacc = {};
  const int swz = (r16 & 7) << 4;
  const int b0 = r16 * 128 + ((g * 16) ^ swz);
  const int b1 = r16 * 128 + ((64 + g * 16) ^ swz);
  const unsigned short* Kb = QKV + (size_t)b * 2048 * 3072 + 2048 + kvh * 64;
  const unsigned short* Vb = VT + (size_t)(b * 512 + kvh * 64) * 2048;
  const int so = wave * 1024 + lane * 16;  // 8 waves x 1KB = 8KB tile

  auto STAGE = [&](int t, int bufi) {
    const int kv0 = t * 64;
    const int row = so >> 7;
    const int c = ((((so >> 4) & 7) ^ (row & 7))) * 8;  // pre-swizzled global source
    GLL16(Kb + (size_t)(kv0 + row) * 3072 + c, (char*)Ks[bufi] + wave * 1024);
    GLL16(Vb + (size_t)row * 2048 + kv0 + c, (char*)Vs[bufi] + wave * 1024);
  };
  auto COMPUTE = [&](int buf) {
    f32x4 sc[4];
    __builtin_amdgcn_s_setprio(1);
#pragma unroll
    for (int jt = 0; jt < 4; ++jt) {
      short8 kf0 = *(const short8*)((const char*)Ks[buf] + jt * 2048 + b0);
      short8 kf1 = *(const short8*)((const char*)Ks[buf] + jt * 2048 + b1);
      f32x4 z = {-8.f, -8.f, -8.f, -8.f};
      z = __builtin_amdgcn_mfma_f32_16x16x32_bf16(kf0, qf[0], z, 0, 0, 0);
      z = __builtin_amdgcn_mfma_f32_16x16x32_bf16(kf1, qf[1], z, 0, 0, 0);
      sc[jt] = z;
    }
    __builtin_amdgcn_s_setprio(0);
    short8 pa[2];
    {
      unsigned pk[4][2];
#pragma unroll
      for (int jt = 0; jt < 4; ++jt) {
        float p0 = __builtin_amdgcn_exp2f(sc[jt][0]);
        float p1 = __builtin_amdgcn_exp2f(sc[jt][1]);
        float p2 = __builtin_amdgcn_exp2f(sc[jt][2]);
        float p3 = __builtin_amdgcn_exp2f(sc[jt][3]);
        asm("v_cvt_pk_bf16_f32 %0, %1, %2" : "=v"(pk[jt][0]) : "v"(p0), "v"(p1));
        asm("v_cvt_pk_bf16_f32 %0, %1, %2" : "=v"(pk[jt][1]) : "v"(p2), "v"(p3));
      }
#pragma unroll
      for (int kh = 0; kh < 2; ++kh) {
        union { unsigned u[4]; short8 s; } pu;
        pu.u[0] = pk[2 * kh][0]; pu.u[1] = pk[2 * kh][1];
        pu.u[2] = pk[2 * kh + 1][0]; pu.u[3] = pk[2 * kh + 1][1];
        pa[kh] = pu.s;
      }
    }
    __builtin_amdgcn_s_setprio(1);
    lacc = __builtin_amdgcn_mfma_f32_16x16x32_bf16(pa[0], ones.s, lacc, 0, 0, 0);
    lacc = __builtin_amdgcn_mfma_f32_16x16x32_bf16(pa[1], ones.s, lacc, 0, 0, 0);
#pragma unroll
    for (int dt = 0; dt < 4; ++dt) {
      short8 vf0 = *(const short8*)((const char*)Vs[buf] + dt * 2048 + b0);
      short8 vf1 = *(const short8*)((const char*)Vs[buf] + dt * 2048 + b1);
      oa[dt] = __builtin_amdgcn_mfma_f32_16x16x32_bf16(pa[0], vf0, oa[dt], 0, 0, 0);
      oa[dt] = __builtin_amdgcn_mfma_f32_16x16x32_bf16(pa[1], vf1, oa[dt], 0, 0, 0);
    }
    __builtin_amdgcn_s_setprio(0);
  };

  STAGE(0, 0);
  STAGE(1, 1);
  __syncthreads();
  for (int j = 0; j < 16; ++j) {
    const int cur = (j & 1) << 1;           // 0 or 2
    if (j < 15) {
      STAGE(2 * j + 2, cur ^ 2);            // idle pair
      STAGE(2 * j + 3, (cur ^ 2) + 1);
    }
    COMPUTE(cur);                           // tile 2j
    COMPUTE(cur + 1);                       // tile 2j+1
    __syncthreads();                        // drains pair staging + ends pair reads
  }
  // ---- normalize: lacc already in O-store layout (row = 4g+r, any col) ----
#pragma unroll
  for (int dt = 0; dt < 4; ++dt)
#pragma unroll
    for (int r = 0; r < 4; ++r)
      O[(size_t)(qtok0 + g * 4 + r) * 2048 + h * 64 + dt * 16 + r16] =
          f2bf(oa[dt][r] / lacc[r]);
}

extern "C" void kernel_launch(void* const* d_in, const int* in_sizes, int n_in,
                              void* d_out, int out_size, void* d_ws, size_t ws_size,
                              hipStream_t stream) {
  const float* x  = (const float*)d_in[0];
  const float* Wq = (const float*)d_in[1];
  const float* Wk = (const float*)d_in[2];
  const float* Wv = (const float*)d_in[3];
  const float* Wo = (const float*)d_in[4];
  char* w = (char*)d_ws;
  // workspace layout (bytes): xb 16MB | WqkvT 12MB | WoT 8MB | QKV 24MB | VT 4MB | O 16MB = 80MB
  unsigned short* xb    = (unsigned short*)(w);
  unsigned short* wqkvt = (unsigned short*)(w + 16777216);
  unsigned short* wot   = (unsigned short*)(w + 29360128);
  unsigned short* qkv   = (unsigned short*)(w + 37748736);
  unsigned short* vt    = (unsigned short*)(w + 62914560);
  unsigned short* ob    = (unsigned short*)(w + 67108864);
  float* out = (float*)d_out;

  prep_kernel<<<14336, 256, 0, stream>>>(x, Wq, Wk, Wv, Wo, xb, wqkvt, wot);
  gemm_qkv_kernel<<<768, 512, 0, stream>>>(xb, wqkvt, qkv, vt);
  attn_kernel<<<1024, 512, 0, stream>>>(qkv, vt, ob);
  gemm_out_kernel<<<512, 512, 0, stream>>>(ob, wot, out);
}